// Round 1
// baseline (377.790 us; speedup 1.0000x reference)
//
#include <hip/hip_runtime.h>
#include <math.h>

// Problem constants (fixed by setup_inputs)
#define BB 32
#define NN 1024
#define DD 1024
#define HH 512

// out layout (floats): [one_hot 32*1024*1024][masked_acts 32*1024][kl 32][log_nom 32][log_norm 32]
#define OUT0_OFF 0
#define OUT1_OFF (BB * NN * NN)
#define OUT2_OFF (OUT1_OFF + BB * NN)
#define OUT3_OFF (OUT2_OFF + BB)
#define OUT4_OFF (OUT3_OFF + BB)

// ws layout (bytes): acts fp32 [32768] @0 ; W1T bf16 [512][1024] @131072 ; rank int[32768] @1179648
#define WS_ACTS 0
#define WS_W1T  131072
#define WS_RANK 1179648

typedef __attribute__((ext_vector_type(8))) short short8;
typedef __attribute__((ext_vector_type(4))) float floatx4;

__device__ inline unsigned int f2bf(float x) {  // RNE fp32 -> bf16 bits
    unsigned int u = __builtin_bit_cast(unsigned int, x);
    return (u + 0x7FFFu + ((u >> 16) & 1u)) >> 16;
}

// ---------------------------------------------------------------------------
// K0: transpose + convert W1 [d=1024][h=512] fp32 -> W1T [h=512][d=1024] bf16
// ---------------------------------------------------------------------------
__global__ __launch_bounds__(1024) void w1t_kernel(const float* __restrict__ W1,
                                                   unsigned short* __restrict__ W1T)
{
    __shared__ float T[32][33];
    const int tx = threadIdx.x, ty = threadIdx.y;
    const int d0 = blockIdx.x * 32, h0 = blockIdx.y * 32;
    T[ty][tx] = W1[(d0 + ty) * HH + h0 + tx];
    __syncthreads();
    W1T[(size_t)(h0 + ty) * DD + d0 + tx] = (unsigned short)f2bf(T[tx][ty]);
}

// ---------------------------------------------------------------------------
// K1: MFMA GEMM + fused relu/W2 epilogue.
// Block: 512 threads (8 waves), M-tile 128 rows, N full 512 cols, K-tile 32.
// Wave grid 2(M) x 4(N): wave w owns rows (w>>2)*64..+64, cols (w&3)*128..+128.
// 2-phase pipeline: loads for kk+1 issued into registers right after the mid
// barrier, so L2 latency hides under frag reads + 32 MFMAs of step kk; the
// compiler-inserted vmcnt before next iteration's ds_writes is the only drain.
// M=128 (1 block/CU) halves per-CU L2 traffic for the B re-stage vs M=64.
// ---------------------------------------------------------------------------
#define ASTRIDE 40
#define MT 128
__global__ __launch_bounds__(512, 2) void gemm_acts_kernel(
    const float* __restrict__ q, const unsigned short* __restrict__ W1T,
    const float* __restrict__ b1, const float* __restrict__ W2,
    const float* __restrict__ b2, const float* __restrict__ unoise,
    float* __restrict__ acts_ws, float* __restrict__ out1)
{
    __shared__ short As[MT * ASTRIDE];    // [m][k32] padded to 80 B rows
    __shared__ short Bs[HH * ASTRIDE];    // [n][k32] padded
    __shared__ float red[MT][4];

    const int tid = threadIdx.x;
    const int w = tid >> 6;          // wave 0..7
    const int lane = tid & 63;
    const int c = lane & 15;         // fragment col/row-in-tile
    const int qd = lane >> 4;        // quad 0..3
    const int wr = (w >> 2) * 64;    // wave row base
    const int wc = (w & 3) * 128;    // wave col base
    const int m0 = blockIdx.x * MT;

    floatx4 acc[8][4];
    #pragma unroll
    for (int tn = 0; tn < 8; ++tn)
        #pragma unroll
        for (int tm = 0; tm < 4; ++tm)
            acc[tn][tm] = (floatx4){0.f, 0.f, 0.f, 0.f};

    // staging indices: thread t -> row srow=t/4, k-chunk skp=t%4 (8 floats / 4 units)
    const int srow = tid >> 2;       // 0..127
    const int skp  = tid & 3;        // 0..3
    const float* aptr = q + (size_t)(m0 + srow) * DD + skp * 8;  // + kk*32 per iter
    const uint4* w1t4 = (const uint4*)W1T;  // 16B units: row n = 128 units

    float4 a0, a1;
    uint4 bv[4];

    // prologue: load kk=0 into registers
    {
        const float4* ap = (const float4*)aptr;
        a0 = ap[0]; a1 = ap[1];
        #pragma unroll
        for (int ii = 0; ii < 4; ++ii)
            bv[ii] = w1t4[(size_t)(ii * 128 + srow) * 128 + skp];
    }

    #pragma unroll 1
    for (int kk = 0; kk < 32; ++kk) {
        // write staged regs -> LDS (compiler inserts vmcnt wait here)
        {
            uint4 pk;
            pk.x = f2bf(a0.x) | (f2bf(a0.y) << 16);
            pk.y = f2bf(a0.z) | (f2bf(a0.w) << 16);
            pk.z = f2bf(a1.x) | (f2bf(a1.y) << 16);
            pk.w = f2bf(a1.z) | (f2bf(a1.w) << 16);
            *(uint4*)(&As[srow * ASTRIDE + skp * 8]) = pk;
            #pragma unroll
            for (int ii = 0; ii < 4; ++ii)
                *(uint4*)(&Bs[(ii * 128 + srow) * ASTRIDE + skp * 8]) = bv[ii];
        }
        __syncthreads();
        // issue next tile's loads NOW — they fly during frag reads + MFMA
        if (kk < 31) {
            const float4* ap = (const float4*)(aptr + (kk + 1) * 32);
            a0 = ap[0]; a1 = ap[1];
            #pragma unroll
            for (int ii = 0; ii < 4; ++ii)
                bv[ii] = w1t4[(size_t)(ii * 128 + srow) * 128 + (kk + 1) * 4 + skp];
        }
        // fragments + MFMA (same K order as baseline -> bit-identical acts)
        short8 af[4];
        #pragma unroll
        for (int tm = 0; tm < 4; ++tm)
            af[tm] = *(const short8*)(&As[(wr + tm * 16 + c) * ASTRIDE + qd * 8]);
        #pragma unroll
        for (int tn = 0; tn < 8; ++tn) {
            short8 bf = *(const short8*)(&Bs[(wc + tn * 16 + c) * ASTRIDE + qd * 8]);
            #pragma unroll
            for (int tm = 0; tm < 4; ++tm)
                acc[tn][tm] = __builtin_amdgcn_mfma_f32_16x16x32_bf16(
                    af[tm], bf, acc[tn][tm], 0, 0, 0);
        }
        __syncthreads();  // frag reads done before next iteration's writes
    }

    // epilogue: h = relu(acc + b1); rowsum += h*W2; reduce over 16 cols + 4 col-waves
    float b1v[8], w2v[8];
    #pragma unroll
    for (int tn = 0; tn < 8; ++tn) {
        int col = wc + tn * 16 + c;
        b1v[tn] = b1[col];
        w2v[tn] = W2[col];
    }
    #pragma unroll
    for (int tm = 0; tm < 4; ++tm) {
        #pragma unroll
        for (int r = 0; r < 4; ++r) {
            float p = 0.f;
            #pragma unroll
            for (int tn = 0; tn < 8; ++tn) {
                float v = acc[tn][tm][r] + b1v[tn];
                p = fmaf(fmaxf(v, 0.f), w2v[tn], p);
            }
            p += __shfl_xor(p, 1);
            p += __shfl_xor(p, 2);
            p += __shfl_xor(p, 4);
            p += __shfl_xor(p, 8);
            if (c == 0) red[wr + tm * 16 + qd * 4 + r][w & 3] = p;
        }
    }
    __syncthreads();
    if (tid < MT) {
        float raw = red[tid][0] + red[tid][1] + red[tid][2] + red[tid][3] + b2[0];
        float sp = fmaxf(raw, 0.f) + log1pf(expf(-fabsf(raw)));  // stable softplus
        int row = m0 + tid;
        float av = logf(fmaxf(sp, 1e-5f)) + unoise[row];
        acts_ws[row] = av;
        out1[row]    = av;
    }
}

// ---------------------------------------------------------------------------
// K2: zero the one-hot output region
// ---------------------------------------------------------------------------
__global__ __launch_bounds__(256) void zero_kernel(float4* __restrict__ p, int n4)
{
    int idx = blockIdx.x * blockDim.x + threadIdx.x;
    int stride = gridDim.x * blockDim.x;
    float4 z = make_float4(0.f, 0.f, 0.f, 0.f);
    for (int i = idx; i < n4; i += stride) p[i] = z;
}

// ---------------------------------------------------------------------------
// K3: rank-by-counting, spread across 128 blocks (4 per batch, 256 i each)
// ---------------------------------------------------------------------------
__global__ __launch_bounds__(256) void rank_kernel(
    const float* __restrict__ acts_ws, const float* __restrict__ gumbel,
    int* __restrict__ rank)
{
    __shared__ float P[NN];
    const int b = blockIdx.x >> 2;
    const int chunk = blockIdx.x & 3;
    const int tid = threadIdx.x;
    #pragma unroll
    for (int r = 0; r < 4; ++r) {
        int j = r * 256 + tid;
        P[j] = acts_ws[b * NN + j] + gumbel[b * NN + j];
    }
    __syncthreads();
    const int i = chunk * 256 + tid;
    const float pert = P[i];
    int cnt = 0;
    const float4* P4 = (const float4*)P;
    for (int j4 = 0; j4 < NN / 4; ++j4) {
        float4 pv = P4[j4];  // broadcast
        int j = j4 * 4;
        cnt += (pv.x > pert) || (pv.x == pert && j + 0 < i);
        cnt += (pv.y > pert) || (pv.y == pert && j + 1 < i);
        cnt += (pv.z > pert) || (pv.z == pert && j + 2 < i);
        cnt += (pv.w > pert) || (pv.w == pert && j + 3 < i);
    }
    rank[b * NN + i] = cnt;
}

// ---------------------------------------------------------------------------
// K4: per-batch permutation, one-hot scatter, PL likelihood, kl.
// Wave-level shfl suffix-scan + butterfly reductions: 4 block barriers total
// (baseline had ~50 barriers on a 16-wave block).
// ---------------------------------------------------------------------------
__global__ __launch_bounds__(1024) void permu_stats_kernel(
    const float* __restrict__ acts_ws, const int* __restrict__ rank,
    float* __restrict__ out0, float* __restrict__ out2,
    float* __restrict__ out3, float* __restrict__ out4)
{
    __shared__ float A[NN];
    __shared__ int   IDX[NN];
    __shared__ float WT[16];
    __shared__ float WSUF[17];
    __shared__ float P0[16], P1[16], P2[16];

    const int b = blockIdx.x;
    const int i = threadIdx.x;
    const int lane = i & 63;
    const int w = i >> 6;            // wave 0..15

    float a = acts_ws[b * NN + i];
    A[i] = a;
    IDX[rank[b * NN + i]] = i;
    __syncthreads();                                        // barrier A

    int perm = (i == 0) ? 0 : IDX[i - 1];
    out0[((size_t)b * NN + i) * NN + perm] = 1.0f;

    float e = expf(A[perm]);
    // intra-wave inclusive suffix sum of e
    float s = e;
    #pragma unroll
    for (int off = 1; off < 64; off <<= 1) {
        float v = __shfl_down(s, off);
        if (lane + off < 64) s += v;
    }
    if (lane == 0) WT[w] = s;        // wave total (suffix from lane 0)
    __syncthreads();                                        // barrier B
    if (w == 0) {
        float t = (lane < 16) ? WT[lane] : 0.f;
        #pragma unroll
        for (int off = 1; off < 16; off <<= 1) {
            float v = __shfl_down(t, off);
            if (lane + off < 16) t += v;
        }
        if (lane < 16) WSUF[lane] = t;   // sum over waves >= lane
        if (lane == 0) WSUF[16] = 0.f;
    }
    __syncthreads();                                        // barrier C

    float S = s + WSUF[w + 1];       // full suffix sum_{j>=i} e_j
    float term = logf(e + 1e-20f) - logf(S + 1e-20f);

    // three simultaneous full-wave butterfly reductions
    float r0 = term, r1 = a, r2 = expf(-fmaxf(a, -20.f));
    #pragma unroll
    for (int off = 1; off < 64; off <<= 1) {
        r0 += __shfl_xor(r0, off);
        r1 += __shfl_xor(r1, off);
        r2 += __shfl_xor(r2, off);
    }
    if (lane == 0) { P0[w] = r0; P1[w] = r1; P2[w] = r2; }
    __syncthreads();                                        // barrier D
    if (i == 0) {
        float t0 = 0.f, t1 = 0.f, t2 = 0.f;
        #pragma unroll
        for (int k = 0; k < 16; ++k) { t0 += P0[k]; t1 += P1[k]; t2 += P2[k]; }
        out3[b] = t0;
        out2[b] = -(float)NN + t1 + t2;
        out4[b] = 0.f;
    }
}

extern "C" void kernel_launch(void* const* d_in, const int* in_sizes, int n_in,
                              void* d_out, int out_size, void* d_ws, size_t ws_size,
                              hipStream_t stream)
{
    const float* q      = (const float*)d_in[0];
    const float* W1     = (const float*)d_in[2];
    const float* b1     = (const float*)d_in[3];
    const float* W2     = (const float*)d_in[4];
    const float* b2     = (const float*)d_in[5];
    const float* unoise = (const float*)d_in[6];
    const float* gumbel = (const float*)d_in[7];

    float* out  = (float*)d_out;
    char*  ws   = (char*)d_ws;
    float*          acts = (float*)(ws + WS_ACTS);
    unsigned short* W1T  = (unsigned short*)(ws + WS_W1T);
    int*            rank = (int*)(ws + WS_RANK);

    w1t_kernel<<<dim3(32, 16), dim3(32, 32), 0, stream>>>(W1, W1T);
    gemm_acts_kernel<<<(BB * NN) / MT, 512, 0, stream>>>(q, W1T, b1, W2, b2,
                                                         unoise, acts,
                                                         out + OUT1_OFF);
    zero_kernel<<<8192, 256, 0, stream>>>((float4*)(out + OUT0_OFF),
                                          (BB * NN * NN) / 4);
    rank_kernel<<<BB * 4, 256, 0, stream>>>(acts, gumbel, rank);
    permu_stats_kernel<<<BB, 1024, 0, stream>>>(acts, rank,
                                                out + OUT0_OFF, out + OUT2_OFF,
                                                out + OUT3_OFF, out + OUT4_OFF);
}

// Round 2
// 315.724 us; speedup vs baseline: 1.1966x; 1.1966x over previous
//
#include <hip/hip_runtime.h>
#include <math.h>

// Problem constants (fixed by setup_inputs)
#define BB 32
#define NN 1024
#define DD 1024
#define HH 512

// out layout (floats): [one_hot 32*1024*1024][masked_acts 32*1024][kl 32][log_nom 32][log_norm 32]
#define OUT0_OFF 0
#define OUT1_OFF (BB * NN * NN)
#define OUT2_OFF (OUT1_OFF + BB * NN)
#define OUT3_OFF (OUT2_OFF + BB)
#define OUT4_OFF (OUT3_OFF + BB)

// ws layout (bytes): acts fp32 [32768] @0 ; W1T bf16 [512][1024] @131072 ; rank int[32768] @1179648
#define WS_ACTS 0
#define WS_W1T  131072
#define WS_RANK 1179648

typedef __attribute__((ext_vector_type(8))) short short8;
typedef __attribute__((ext_vector_type(4))) float floatx4;

__device__ inline unsigned int f2bf(float x) {  // RNE fp32 -> bf16 bits
    unsigned int u = __builtin_bit_cast(unsigned int, x);
    return (u + 0x7FFFu + ((u >> 16) & 1u)) >> 16;
}

// async global->LDS DMA, 16 B per lane, LDS dest = wave-uniform base + lane*16
__device__ inline void gload_lds16(const void* g, void* l) {
    __builtin_amdgcn_global_load_lds(
        (const __attribute__((address_space(1))) unsigned int*)g,
        (__attribute__((address_space(3))) unsigned int*)l, 16, 0, 0);
}

// ---------------------------------------------------------------------------
// K0: transpose + convert W1 [d=1024][h=512] fp32 -> W1T [h=512][d=1024] bf16
// ---------------------------------------------------------------------------
__global__ __launch_bounds__(1024) void w1t_kernel(const float* __restrict__ W1,
                                                   unsigned short* __restrict__ W1T)
{
    __shared__ float T[32][33];
    const int tx = threadIdx.x, ty = threadIdx.y;
    const int d0 = blockIdx.x * 32, h0 = blockIdx.y * 32;
    T[ty][tx] = W1[(d0 + ty) * HH + h0 + tx];
    __syncthreads();
    W1T[(size_t)(h0 + ty) * DD + d0 + tx] = (unsigned short)f2bf(T[tx][ty]);
}

// ---------------------------------------------------------------------------
// K1: MFMA GEMM + fused relu/W2 epilogue.  256 threads (4 waves), M=64, N=512,
// K-step 32.  2-phase pipeline (T3 minimum recipe):
//   per iter: issue B DMA(k+1) via global_load_lds (zero VGPR cost) ->
//             pack prefetched A regs(k+1) -> ds_reads + 32 MFMA on tile k ->
//             single s_waitcnt vmcnt(0) lgkmcnt(0) + s_barrier.
// LDS rows are 64 B linear with XOR swizzle byte[5:4] ^= ((row>>1)&3), applied
// BOTH on the DMA source address and the frag reads (rule 21) -> <=2-way
// conflicts (free).  LDS = 2*32K B + 2*4K A + 1K red = 74.75 KB, 2 blocks/CU.
// Registers: acc 128 (AGPR) + ~100 VGPR, staging adds only 8 (A regs) — no
// spill (round-1's 52 MB scratch WRITE_SIZE was the spill cliff at 256 regs).
// ---------------------------------------------------------------------------
#define MT 64
__global__ __launch_bounds__(256, 2) void gemm_acts_kernel(
    const float* __restrict__ q, const unsigned short* __restrict__ W1T,
    const float* __restrict__ b1, const float* __restrict__ W2,
    const float* __restrict__ b2, const float* __restrict__ unoise,
    float* __restrict__ acts_ws, float* __restrict__ out1)
{
    __shared__ short As[2][MT * 32];   // 2 x 4096 B, swizzled 64 B rows
    __shared__ short Bs[2][HH * 32];   // 2 x 32768 B, swizzled 64 B rows
    __shared__ float red[MT][4];

    const int tid  = threadIdx.x;
    const int w    = tid >> 6;         // wave 0..3
    const int lane = tid & 63;
    const int c    = lane & 15;        // fragment row/col-in-tile
    const int qd   = lane >> 4;        // quad 0..3
    const int m0   = blockIdx.x * MT;

    floatx4 acc[8][4];
    #pragma unroll
    for (int tn = 0; tn < 8; ++tn)
        #pragma unroll
        for (int tm = 0; tm < 4; ++tm)
            acc[tn][tm] = (floatx4){0.f, 0.f, 0.f, 0.f};

    // DMA source byte offsets into W1T for this wave's 8 chunks (1 KB each).
    // Chunk m = w*8+j covers rows n = m*16 + (lane>>2); lane writes LDS bytes
    // [m*1024 + lane*16, +16) = row n, stored col c0=(lane&3)*16.  Stored col
    // c0 holds element bytes c0 ^ (s<<4), s = (n>>1)&3  (involution).
    int boff[8];
    #pragma unroll
    for (int j = 0; j < 8; ++j) {
        int n  = (w * 8 + j) * 16 + (lane >> 2);
        int c0 = (lane & 3) * 16;
        int s  = (n >> 1) & 3;
        boff[j] = n * 2048 + (c0 ^ (s << 4));
    }
    const char* w1tb = (const char*)W1T;

    // A staging: thread -> row srow=tid/4, 8 floats at (tid%4)*8
    const int srow = tid >> 2, skp = tid & 3;
    const float* aptr = q + (size_t)(m0 + srow) * DD + skp * 8;
    const int asw = (skp * 16) ^ (((srow >> 1) & 3) << 4);  // swizzled byte col

    // loop-invariant frag-read byte offsets
    int aoff[4], boffr[8];
    #pragma unroll
    for (int tm = 0; tm < 4; ++tm) {
        int r = tm * 16 + c;
        aoff[tm] = r * 64 + ((qd * 16) ^ (((r >> 1) & 3) << 4));
    }
    #pragma unroll
    for (int tn = 0; tn < 8; ++tn) {
        int n = w * 128 + tn * 16 + c;
        boffr[tn] = n * 64 + ((qd * 16) ^ (((n >> 1) & 3) << 4));
    }

    float4 a0, a1;

    // ---- prologue: B DMA(0) -> Bs[0]; pack A(0) -> As[0]; preload A(1) ----
    #pragma unroll
    for (int j = 0; j < 8; ++j)
        gload_lds16(w1tb + boff[j], (char*)(&Bs[0][0]) + (w * 8 + j) * 1024);
    {
        const float4* ap = (const float4*)aptr;
        float4 v0 = ap[0], v1 = ap[1];
        uint4 pk;
        pk.x = f2bf(v0.x) | (f2bf(v0.y) << 16);
        pk.y = f2bf(v0.z) | (f2bf(v0.w) << 16);
        pk.z = f2bf(v1.x) | (f2bf(v1.y) << 16);
        pk.w = f2bf(v1.z) | (f2bf(v1.w) << 16);
        *(uint4*)((char*)(&As[0][0]) + srow * 64 + asw) = pk;
        const float4* ap1 = (const float4*)(aptr + 32);
        a0 = ap1[0]; a1 = ap1[1];
    }
    asm volatile("s_waitcnt vmcnt(0) lgkmcnt(0)" ::: "memory");
    __builtin_amdgcn_s_barrier();

    #pragma unroll 1
    for (int kk = 0; kk < 32; ++kk) {
        const int cur = kk & 1, nxt = cur ^ 1;
        const int kb = (kk < 31) ? kk + 1 : 31;   // clamped: last iter redundant
        // issue B DMA(kk+1) -> Bs[nxt] (safe: all waves passed prev barrier)
        #pragma unroll
        for (int j = 0; j < 8; ++j)
            gload_lds16(w1tb + (boff[j] + kb * 64),
                        (char*)(&Bs[nxt][0]) + (w * 8 + j) * 1024);
        // pack A(kk+1) (regs drained by prev iter's vmcnt(0)) -> As[nxt]
        {
            uint4 pk;
            pk.x = f2bf(a0.x) | (f2bf(a0.y) << 16);
            pk.y = f2bf(a0.z) | (f2bf(a0.w) << 16);
            pk.z = f2bf(a1.x) | (f2bf(a1.y) << 16);
            pk.w = f2bf(a1.z) | (f2bf(a1.w) << 16);
            *(uint4*)((char*)(&As[nxt][0]) + srow * 64 + asw) = pk;
        }
        // issue A loads(kk+2) into the just-consumed regs
        {
            const int ka = (kk < 30) ? kk + 2 : 31;
            const float4* ap = (const float4*)(aptr + ka * 32);
            a0 = ap[0]; a1 = ap[1];
        }
        // frag reads + MFMA on tile kk (compiler inserts lgkmcnt for deps)
        short8 af[4];
        #pragma unroll
        for (int tm = 0; tm < 4; ++tm)
            af[tm] = *(const short8*)((const char*)(&As[cur][0]) + aoff[tm]);
        #pragma unroll
        for (int tn = 0; tn < 8; ++tn) {
            short8 bf = *(const short8*)((const char*)(&Bs[cur][0]) + boffr[tn]);
            #pragma unroll
            for (int tm = 0; tm < 4; ++tm)
                acc[tn][tm] = __builtin_amdgcn_mfma_f32_16x16x32_bf16(
                    af[tm], bf, acc[tn][tm], 0, 0, 0);
        }
        // single drain per K-step: DMA + A loads + ds_writes, then barrier
        asm volatile("s_waitcnt vmcnt(0) lgkmcnt(0)" ::: "memory");
        __builtin_amdgcn_s_barrier();
    }

    // epilogue: h = relu(acc + b1); rowsum += h*W2; reduce 16 cols + 4 waves
    float b1v[8], w2v[8];
    #pragma unroll
    for (int tn = 0; tn < 8; ++tn) {
        int col = w * 128 + tn * 16 + c;
        b1v[tn] = b1[col];
        w2v[tn] = W2[col];
    }
    #pragma unroll
    for (int tm = 0; tm < 4; ++tm) {
        #pragma unroll
        for (int r = 0; r < 4; ++r) {
            float p = 0.f;
            #pragma unroll
            for (int tn = 0; tn < 8; ++tn) {
                float v = acc[tn][tm][r] + b1v[tn];
                p = fmaf(fmaxf(v, 0.f), w2v[tn], p);
            }
            p += __shfl_xor(p, 1);
            p += __shfl_xor(p, 2);
            p += __shfl_xor(p, 4);
            p += __shfl_xor(p, 8);
            if (c == 0) red[tm * 16 + qd * 4 + r][w] = p;
        }
    }
    __syncthreads();
    if (tid < MT) {
        float raw = red[tid][0] + red[tid][1] + red[tid][2] + red[tid][3] + b2[0];
        float sp = fmaxf(raw, 0.f) + log1pf(expf(-fabsf(raw)));  // stable softplus
        int row = m0 + tid;
        float av = logf(fmaxf(sp, 1e-5f)) + unoise[row];
        acts_ws[row] = av;
        out1[row]    = av;
    }
}

// ---------------------------------------------------------------------------
// K2: zero the one-hot output region
// ---------------------------------------------------------------------------
__global__ __launch_bounds__(256) void zero_kernel(float4* __restrict__ p, int n4)
{
    int idx = blockIdx.x * blockDim.x + threadIdx.x;
    int stride = gridDim.x * blockDim.x;
    float4 z = make_float4(0.f, 0.f, 0.f, 0.f);
    for (int i = idx; i < n4; i += stride) p[i] = z;
}

// ---------------------------------------------------------------------------
// K3: rank-by-counting, spread across 128 blocks (4 per batch, 256 i each)
// ---------------------------------------------------------------------------
__global__ __launch_bounds__(256) void rank_kernel(
    const float* __restrict__ acts_ws, const float* __restrict__ gumbel,
    int* __restrict__ rank)
{
    __shared__ float P[NN];
    const int b = blockIdx.x >> 2;
    const int chunk = blockIdx.x & 3;
    const int tid = threadIdx.x;
    #pragma unroll
    for (int r = 0; r < 4; ++r) {
        int j = r * 256 + tid;
        P[j] = acts_ws[b * NN + j] + gumbel[b * NN + j];
    }
    __syncthreads();
    const int i = chunk * 256 + tid;
    const float pert = P[i];
    int cnt = 0;
    const float4* P4 = (const float4*)P;
    for (int j4 = 0; j4 < NN / 4; ++j4) {
        float4 pv = P4[j4];  // broadcast
        int j = j4 * 4;
        cnt += (pv.x > pert) || (pv.x == pert && j + 0 < i);
        cnt += (pv.y > pert) || (pv.y == pert && j + 1 < i);
        cnt += (pv.z > pert) || (pv.z == pert && j + 2 < i);
        cnt += (pv.w > pert) || (pv.w == pert && j + 3 < i);
    }
    rank[b * NN + i] = cnt;
}

// ---------------------------------------------------------------------------
// K4: per-batch permutation, one-hot scatter, PL likelihood, kl.
// Wave-level shfl suffix-scan + butterfly reductions: 4 block barriers total.
// ---------------------------------------------------------------------------
__global__ __launch_bounds__(1024) void permu_stats_kernel(
    const float* __restrict__ acts_ws, const int* __restrict__ rank,
    float* __restrict__ out0, float* __restrict__ out2,
    float* __restrict__ out3, float* __restrict__ out4)
{
    __shared__ float A[NN];
    __shared__ int   IDX[NN];
    __shared__ float WT[16];
    __shared__ float WSUF[17];
    __shared__ float P0[16], P1[16], P2[16];

    const int b = blockIdx.x;
    const int i = threadIdx.x;
    const int lane = i & 63;
    const int w = i >> 6;            // wave 0..15

    float a = acts_ws[b * NN + i];
    A[i] = a;
    IDX[rank[b * NN + i]] = i;
    __syncthreads();                                        // barrier A

    int perm = (i == 0) ? 0 : IDX[i - 1];
    out0[((size_t)b * NN + i) * NN + perm] = 1.0f;

    float e = expf(A[perm]);
    // intra-wave inclusive suffix sum of e
    float s = e;
    #pragma unroll
    for (int off = 1; off < 64; off <<= 1) {
        float v = __shfl_down(s, off);
        if (lane + off < 64) s += v;
    }
    if (lane == 0) WT[w] = s;        // wave total (suffix from lane 0)
    __syncthreads();                                        // barrier B
    if (w == 0) {
        float t = (lane < 16) ? WT[lane] : 0.f;
        #pragma unroll
        for (int off = 1; off < 16; off <<= 1) {
            float v = __shfl_down(t, off);
            if (lane + off < 16) t += v;
        }
        if (lane < 16) WSUF[lane] = t;   // sum over waves >= lane
        if (lane == 0) WSUF[16] = 0.f;
    }
    __syncthreads();                                        // barrier C

    float S = s + WSUF[w + 1];       // full suffix sum_{j>=i} e_j
    float term = logf(e + 1e-20f) - logf(S + 1e-20f);

    // three simultaneous full-wave butterfly reductions
    float r0 = term, r1 = a, r2 = expf(-fmaxf(a, -20.f));
    #pragma unroll
    for (int off = 1; off < 64; off <<= 1) {
        r0 += __shfl_xor(r0, off);
        r1 += __shfl_xor(r1, off);
        r2 += __shfl_xor(r2, off);
    }
    if (lane == 0) { P0[w] = r0; P1[w] = r1; P2[w] = r2; }
    __syncthreads();                                        // barrier D
    if (i == 0) {
        float t0 = 0.f, t1 = 0.f, t2 = 0.f;
        #pragma unroll
        for (int k = 0; k < 16; ++k) { t0 += P0[k]; t1 += P1[k]; t2 += P2[k]; }
        out3[b] = t0;
        out2[b] = -(float)NN + t1 + t2;
        out4[b] = 0.f;
    }
}

extern "C" void kernel_launch(void* const* d_in, const int* in_sizes, int n_in,
                              void* d_out, int out_size, void* d_ws, size_t ws_size,
                              hipStream_t stream)
{
    const float* q      = (const float*)d_in[0];
    const float* W1     = (const float*)d_in[2];
    const float* b1     = (const float*)d_in[3];
    const float* W2     = (const float*)d_in[4];
    const float* b2     = (const float*)d_in[5];
    const float* unoise = (const float*)d_in[6];
    const float* gumbel = (const float*)d_in[7];

    float* out  = (float*)d_out;
    char*  ws   = (char*)d_ws;
    float*          acts = (float*)(ws + WS_ACTS);
    unsigned short* W1T  = (unsigned short*)(ws + WS_W1T);
    int*            rank = (int*)(ws + WS_RANK);

    w1t_kernel<<<dim3(32, 16), dim3(32, 32), 0, stream>>>(W1, W1T);
    gemm_acts_kernel<<<(BB * NN) / MT, 256, 0, stream>>>(q, W1T, b1, W2, b2,
                                                         unoise, acts,
                                                         out + OUT1_OFF);
    zero_kernel<<<8192, 256, 0, stream>>>((float4*)(out + OUT0_OFF),
                                          (BB * NN * NN) / 4);
    rank_kernel<<<BB * 4, 256, 0, stream>>>(acts, gumbel, rank);
    permu_stats_kernel<<<BB, 1024, 0, stream>>>(acts, rank,
                                                out + OUT0_OFF, out + OUT2_OFF,
                                                out + OUT3_OFF, out + OUT4_OFF);
}

// Round 3
// 310.923 us; speedup vs baseline: 1.2151x; 1.0154x over previous
//
#include <hip/hip_runtime.h>
#include <math.h>

// Problem constants (fixed by setup_inputs)
#define BB 32
#define NN 1024
#define DD 1024
#define HH 512

// out layout (floats): [one_hot 32*1024*1024][masked_acts 32*1024][kl 32][log_nom 32][log_norm 32]
#define OUT0_OFF 0
#define OUT1_OFF (BB * NN * NN)
#define OUT2_OFF (OUT1_OFF + BB * NN)
#define OUT3_OFF (OUT2_OFF + BB)
#define OUT4_OFF (OUT3_OFF + BB)

// ws layout (bytes): acts fp32 [32768] @0 ; W1T bf16 [512][1024] @131072 ; rank int[32768] @1179648
#define WS_ACTS 0
#define WS_W1T  131072
#define WS_RANK 1179648

typedef __attribute__((ext_vector_type(8))) short short8;
typedef __attribute__((ext_vector_type(4))) float floatx4;

__device__ inline unsigned int f2bf(float x) {  // RNE fp32 -> bf16 bits
    unsigned int u = __builtin_bit_cast(unsigned int, x);
    return (u + 0x7FFFu + ((u >> 16) & 1u)) >> 16;
}

// async global->LDS DMA, 16 B per lane, LDS dest = wave-uniform base + lane*16
__device__ inline void gload_lds16(const void* g, void* l) {
    __builtin_amdgcn_global_load_lds(
        (const __attribute__((address_space(1))) unsigned int*)g,
        (__attribute__((address_space(3))) unsigned int*)l, 16, 0, 0);
}

// ---------------------------------------------------------------------------
// K0: transpose + convert W1 [d=1024][h=512] fp32 -> W1T [h=512][d=1024] bf16
// ---------------------------------------------------------------------------
__global__ __launch_bounds__(1024) void w1t_kernel(const float* __restrict__ W1,
                                                   unsigned short* __restrict__ W1T)
{
    __shared__ float T[32][33];
    const int tx = threadIdx.x, ty = threadIdx.y;
    const int d0 = blockIdx.x * 32, h0 = blockIdx.y * 32;
    T[ty][tx] = W1[(d0 + ty) * HH + h0 + tx];
    __syncthreads();
    W1T[(size_t)(h0 + ty) * DD + d0 + tx] = (unsigned short)f2bf(T[tx][ty]);
}

// ---------------------------------------------------------------------------
// K1: MFMA GEMM + fused relu/W2 epilogue.
// 512 threads (8 waves), M=128, N=512, K-step 32, grid 256 = 1 block/CU
// (halves per-CU B re-stage traffic vs M=64/2-blocks).
// Wave grid 2(M) x 4(N): wave w owns rows (w>>2)*64..+64, cols (w&3)*128..+128
// -> acc[8][4] per wave, identical compute structure to the round-2 kernel.
// Single barrier per K-step, drain rotated to TOP of iteration:
//   { vmcnt(0)+lgkmcnt(0); s_barrier; issue B-DMA(k+1)+pack A(k+1)+
//     issue A-loads(k+2); ds_read + 32 MFMA on tile k }
// so all memory ops issued in iter k have a FULL iteration to complete before
// the drain at top of iter k+1 (round-2 drained in the same iteration ->
// per-step latency exposure, MfmaUtil 16%).
// B staging: zero-VGPR via global_load_lds; A staging: 8 VGPRs, depth 2.
// LDS rows 64 B linear, XOR swizzle byte[5:4] ^= ((row>>1)&3) on BOTH the DMA
// source address and the frag reads (rule 21) -> measured 0 bank conflicts.
// LDS: 2*32K B + 2*8K A + 2K red = 82 KB.  Regs ~ 128 AGPR + ~90 VGPR < 256.
// ---------------------------------------------------------------------------
#define MT 128
__global__ __launch_bounds__(512, 2) void gemm_acts_kernel(
    const float* __restrict__ q, const unsigned short* __restrict__ W1T,
    const float* __restrict__ b1, const float* __restrict__ W2,
    const float* __restrict__ b2, const float* __restrict__ unoise,
    float* __restrict__ acts_ws, float* __restrict__ out1)
{
    __shared__ short As[2][MT * 32];   // 2 x 8192 B, swizzled 64 B rows
    __shared__ short Bs[2][HH * 32];   // 2 x 32768 B, swizzled 64 B rows
    __shared__ float red[MT][4];

    const int tid  = threadIdx.x;
    const int w    = tid >> 6;         // wave 0..7
    const int lane = tid & 63;
    const int c    = lane & 15;        // fragment row/col-in-tile
    const int qd   = lane >> 4;        // quad 0..3
    const int wr   = (w >> 2) * 64;    // wave row base (0 or 64)
    const int wc   = (w & 3) * 128;    // wave col base
    const int m0   = blockIdx.x * MT;

    floatx4 acc[8][4];
    #pragma unroll
    for (int tn = 0; tn < 8; ++tn)
        #pragma unroll
        for (int tm = 0; tm < 4; ++tm)
            acc[tn][tm] = (floatx4){0.f, 0.f, 0.f, 0.f};

    // B DMA: 32 chunks of 1 KB (16 rows x 64 B); wave w stages chunks w*4+j.
    // Lane covers row n = chunk*16 + (lane>>2), stored col c0 = (lane&3)*16.
    // Stored col c0 holds element bytes c0 ^ (s<<4), s = (n>>1)&3 (involution),
    // so pre-swizzle the SOURCE address (m173 pattern).
    int boff[4];
    #pragma unroll
    for (int j = 0; j < 4; ++j) {
        int n  = (w * 4 + j) * 16 + (lane >> 2);
        int c0 = (lane & 3) * 16;
        int s  = (n >> 1) & 3;
        boff[j] = n * 2048 + (c0 ^ (s << 4));
    }
    const char* w1tb = (const char*)W1T;

    // A staging: thread -> row srow=tid/4 (0..127), 8 floats at (tid%4)*8
    const int srow = tid >> 2, skp = tid & 3;
    const float* aptr = q + (size_t)(m0 + srow) * DD + skp * 8;
    const int asw = (skp * 16) ^ (((srow >> 1) & 3) << 4);  // swizzled byte col

    // loop-invariant frag-read byte offsets (same XOR on the read side)
    int aoff[4], boffr[8];
    #pragma unroll
    for (int tm = 0; tm < 4; ++tm) {
        int r = wr + tm * 16 + c;
        aoff[tm] = r * 64 + ((qd * 16) ^ (((r >> 1) & 3) << 4));
    }
    #pragma unroll
    for (int tn = 0; tn < 8; ++tn) {
        int n = wc + tn * 16 + c;
        boffr[tn] = n * 64 + ((qd * 16) ^ (((n >> 1) & 3) << 4));
    }

    float4 a0, a1;

    // ---- prologue: issue B DMA(0) -> Bs[0]; pack A(0) -> As[0] (sync);
    //      issue A-loads(1) into regs ----
    #pragma unroll
    for (int j = 0; j < 4; ++j)
        gload_lds16(w1tb + boff[j], (char*)(&Bs[0][0]) + (w * 4 + j) * 1024);
    {
        const float4* ap = (const float4*)aptr;
        float4 v0 = ap[0], v1 = ap[1];
        uint4 pk;
        pk.x = f2bf(v0.x) | (f2bf(v0.y) << 16);
        pk.y = f2bf(v0.z) | (f2bf(v0.w) << 16);
        pk.z = f2bf(v1.x) | (f2bf(v1.y) << 16);
        pk.w = f2bf(v1.z) | (f2bf(v1.w) << 16);
        *(uint4*)((char*)(&As[0][0]) + srow * 64 + asw) = pk;
        const float4* ap1 = (const float4*)(aptr + 32);
        a0 = ap1[0]; a1 = ap1[1];
    }

    #pragma unroll 1
    for (int kk = 0; kk < 32; ++kk) {
        // drain: everything issued in iter kk-1 (or prologue) had a full
        // iteration in flight -> this wait is short.  Then one barrier.
        asm volatile("s_waitcnt vmcnt(0) lgkmcnt(0)" ::: "memory");
        __builtin_amdgcn_s_barrier();

        const int cur = kk & 1, nxt = cur ^ 1;
        if (kk < 31) {
            // issue B DMA(kk+1) -> Bs[nxt]  (safe: all waves passed barrier,
            // so iter kk-1's readers of Bs[nxt] are done)
            #pragma unroll
            for (int j = 0; j < 4; ++j)
                gload_lds16(w1tb + (boff[j] + (kk + 1) * 64),
                            (char*)(&Bs[nxt][0]) + (w * 4 + j) * 1024);
            // pack A(kk+1) (regs drained by the vmcnt above) -> As[nxt]
            uint4 pk;
            pk.x = f2bf(a0.x) | (f2bf(a0.y) << 16);
            pk.y = f2bf(a0.z) | (f2bf(a0.w) << 16);
            pk.z = f2bf(a1.x) | (f2bf(a1.y) << 16);
            pk.w = f2bf(a1.z) | (f2bf(a1.w) << 16);
            *(uint4*)((char*)(&As[nxt][0]) + srow * 64 + asw) = pk;
            // issue A loads(kk+2) (WAR on a0/a1 resolved by SSA renaming)
            const int ka = (kk < 30) ? kk + 2 : 31;
            const float4* ap = (const float4*)(aptr + ka * 32);
            a0 = ap[0]; a1 = ap[1];
        }
        // frag reads + MFMA on tile kk (compiler inserts lgkmcnt for deps)
        __builtin_amdgcn_s_setprio(1);
        short8 af[4];
        #pragma unroll
        for (int tm = 0; tm < 4; ++tm)
            af[tm] = *(const short8*)((const char*)(&As[cur][0]) + aoff[tm]);
        #pragma unroll
        for (int tn = 0; tn < 8; ++tn) {
            short8 bf = *(const short8*)((const char*)(&Bs[cur][0]) + boffr[tn]);
            #pragma unroll
            for (int tm = 0; tm < 4; ++tm)
                acc[tn][tm] = __builtin_amdgcn_mfma_f32_16x16x32_bf16(
                    af[tm], bf, acc[tn][tm], 0, 0, 0);
        }
        __builtin_amdgcn_s_setprio(0);
    }

    // epilogue: h = relu(acc + b1); rowsum += h*W2; reduce 16 cols + 4 N-waves
    float b1v[8], w2v[8];
    #pragma unroll
    for (int tn = 0; tn < 8; ++tn) {
        int col = wc + tn * 16 + c;
        b1v[tn] = b1[col];
        w2v[tn] = W2[col];
    }
    #pragma unroll
    for (int tm = 0; tm < 4; ++tm) {
        #pragma unroll
        for (int r = 0; r < 4; ++r) {
            float p = 0.f;
            #pragma unroll
            for (int tn = 0; tn < 8; ++tn) {
                float v = acc[tn][tm][r] + b1v[tn];
                p = fmaf(fmaxf(v, 0.f), w2v[tn], p);
            }
            p += __shfl_xor(p, 1);
            p += __shfl_xor(p, 2);
            p += __shfl_xor(p, 4);
            p += __shfl_xor(p, 8);
            if (c == 0) red[wr + tm * 16 + qd * 4 + r][w & 3] = p;
        }
    }
    __syncthreads();
    if (tid < MT) {
        float raw = red[tid][0] + red[tid][1] + red[tid][2] + red[tid][3] + b2[0];
        float sp = fmaxf(raw, 0.f) + log1pf(expf(-fabsf(raw)));  // stable softplus
        int row = m0 + tid;
        float av = logf(fmaxf(sp, 1e-5f)) + unoise[row];
        acts_ws[row] = av;
        out1[row]    = av;
    }
}

// ---------------------------------------------------------------------------
// K2: zero the one-hot output region
// ---------------------------------------------------------------------------
__global__ __launch_bounds__(256) void zero_kernel(float4* __restrict__ p, int n4)
{
    int idx = blockIdx.x * blockDim.x + threadIdx.x;
    int stride = gridDim.x * blockDim.x;
    float4 z = make_float4(0.f, 0.f, 0.f, 0.f);
    for (int i = idx; i < n4; i += stride) p[i] = z;
}

// ---------------------------------------------------------------------------
// K3: rank-by-counting, spread across 128 blocks (4 per batch, 256 i each)
// ---------------------------------------------------------------------------
__global__ __launch_bounds__(256) void rank_kernel(
    const float* __restrict__ acts_ws, const float* __restrict__ gumbel,
    int* __restrict__ rank)
{
    __shared__ float P[NN];
    const int b = blockIdx.x >> 2;
    const int chunk = blockIdx.x & 3;
    const int tid = threadIdx.x;
    #pragma unroll
    for (int r = 0; r < 4; ++r) {
        int j = r * 256 + tid;
        P[j] = acts_ws[b * NN + j] + gumbel[b * NN + j];
    }
    __syncthreads();
    const int i = chunk * 256 + tid;
    const float pert = P[i];
    int cnt = 0;
    const float4* P4 = (const float4*)P;
    for (int j4 = 0; j4 < NN / 4; ++j4) {
        float4 pv = P4[j4];  // broadcast
        int j = j4 * 4;
        cnt += (pv.x > pert) || (pv.x == pert && j + 0 < i);
        cnt += (pv.y > pert) || (pv.y == pert && j + 1 < i);
        cnt += (pv.z > pert) || (pv.z == pert && j + 2 < i);
        cnt += (pv.w > pert) || (pv.w == pert && j + 3 < i);
    }
    rank[b * NN + i] = cnt;
}

// ---------------------------------------------------------------------------
// K4: per-batch permutation, one-hot scatter, PL likelihood, kl.
// Wave-level shfl suffix-scan + butterfly reductions: 4 block barriers total.
// ---------------------------------------------------------------------------
__global__ __launch_bounds__(1024) void permu_stats_kernel(
    const float* __restrict__ acts_ws, const int* __restrict__ rank,
    float* __restrict__ out0, float* __restrict__ out2,
    float* __restrict__ out3, float* __restrict__ out4)
{
    __shared__ float A[NN];
    __shared__ int   IDX[NN];
    __shared__ float WT[16];
    __shared__ float WSUF[17];
    __shared__ float P0[16], P1[16], P2[16];

    const int b = blockIdx.x;
    const int i = threadIdx.x;
    const int lane = i & 63;
    const int w = i >> 6;            // wave 0..15

    float a = acts_ws[b * NN + i];
    A[i] = a;
    IDX[rank[b * NN + i]] = i;
    __syncthreads();                                        // barrier A

    int perm = (i == 0) ? 0 : IDX[i - 1];
    out0[((size_t)b * NN + i) * NN + perm] = 1.0f;

    float e = expf(A[perm]);
    // intra-wave inclusive suffix sum of e
    float s = e;
    #pragma unroll
    for (int off = 1; off < 64; off <<= 1) {
        float v = __shfl_down(s, off);
        if (lane + off < 64) s += v;
    }
    if (lane == 0) WT[w] = s;        // wave total (suffix from lane 0)
    __syncthreads();                                        // barrier B
    if (w == 0) {
        float t = (lane < 16) ? WT[lane] : 0.f;
        #pragma unroll
        for (int off = 1; off < 16; off <<= 1) {
            float v = __shfl_down(t, off);
            if (lane + off < 16) t += v;
        }
        if (lane < 16) WSUF[lane] = t;   // sum over waves >= lane
        if (lane == 0) WSUF[16] = 0.f;
    }
    __syncthreads();                                        // barrier C

    float S = s + WSUF[w + 1];       // full suffix sum_{j>=i} e_j
    float term = logf(e + 1e-20f) - logf(S + 1e-20f);

    // three simultaneous full-wave butterfly reductions
    float r0 = term, r1 = a, r2 = expf(-fmaxf(a, -20.f));
    #pragma unroll
    for (int off = 1; off < 64; off <<= 1) {
        r0 += __shfl_xor(r0, off);
        r1 += __shfl_xor(r1, off);
        r2 += __shfl_xor(r2, off);
    }
    if (lane == 0) { P0[w] = r0; P1[w] = r1; P2[w] = r2; }
    __syncthreads();                                        // barrier D
    if (i == 0) {
        float t0 = 0.f, t1 = 0.f, t2 = 0.f;
        #pragma unroll
        for (int k = 0; k < 16; ++k) { t0 += P0[k]; t1 += P1[k]; t2 += P2[k]; }
        out3[b] = t0;
        out2[b] = -(float)NN + t1 + t2;
        out4[b] = 0.f;
    }
}

extern "C" void kernel_launch(void* const* d_in, const int* in_sizes, int n_in,
                              void* d_out, int out_size, void* d_ws, size_t ws_size,
                              hipStream_t stream)
{
    const float* q      = (const float*)d_in[0];
    const float* W1     = (const float*)d_in[2];
    const float* b1     = (const float*)d_in[3];
    const float* W2     = (const float*)d_in[4];
    const float* b2     = (const float*)d_in[5];
    const float* unoise = (const float*)d_in[6];
    const float* gumbel = (const float*)d_in[7];

    float* out  = (float*)d_out;
    char*  ws   = (char*)d_ws;
    float*          acts = (float*)(ws + WS_ACTS);
    unsigned short* W1T  = (unsigned short*)(ws + WS_W1T);
    int*            rank = (int*)(ws + WS_RANK);

    w1t_kernel<<<dim3(32, 16), dim3(32, 32), 0, stream>>>(W1, W1T);
    gemm_acts_kernel<<<(BB * NN) / MT, 512, 0, stream>>>(q, W1T, b1, W2, b2,
                                                         unoise, acts,
                                                         out + OUT1_OFF);
    zero_kernel<<<8192, 256, 0, stream>>>((float4*)(out + OUT0_OFF),
                                          (BB * NN * NN) / 4);
    rank_kernel<<<BB * 4, 256, 0, stream>>>(acts, gumbel, rank);
    permu_stats_kernel<<<BB, 1024, 0, stream>>>(acts, rank,
                                                out + OUT0_OFF, out + OUT2_OFF,
                                                out + OUT3_OFF, out + OUT4_OFF);
}